// Round 6
// baseline (261.953 us; speedup 1.0000x reference)
//
#include <hip/hip_runtime.h>
#include <math.h>

#define DIM   1024
#define NH    16
#define HD    64
#define GRP   128
#define BB    2
#define TT    2048
#define MROWS (BB*TT)   // 4096

typedef __attribute__((ext_vector_type(8))) short s16x8;
typedef __attribute__((ext_vector_type(4))) float f32x4;
typedef __attribute__((ext_vector_type(4))) int   i32x4;
typedef __attribute__((ext_vector_type(16))) int  i32x16;

__device__ inline float wave_max(float v){
    for(int off=32; off; off>>=1) v = fmaxf(v, __shfl_xor(v, off));
    return v;
}

__device__ inline unsigned short f2bf(float x){
    union { float f; unsigned u; } v; v.f = x;
    unsigned r = v.u + 0x7fffu + ((v.u >> 16) & 1u);
    return (unsigned short)(r >> 16);
}

#if __has_builtin(__builtin_amdgcn_cvt_pk_bf16_f32)
typedef __bf16 bf16x2 __attribute__((ext_vector_type(2)));
__device__ inline unsigned pk2(float a, float b){
    union { bf16x2 v; unsigned u; } c;
    c.v = __builtin_amdgcn_cvt_pk_bf16_f32(a, b);
    return c.u;
}
#else
__device__ inline unsigned pk2(float a, float b){
    return (unsigned)f2bf(a) | ((unsigned)f2bf(b) << 16);
}
#endif

#if __has_builtin(__builtin_amdgcn_exp2f)
__device__ inline float fexp2(float x){ return __builtin_amdgcn_exp2f(x); }
#else
__device__ inline float fexp2(float x){ return exp2f(x); }
#endif

__device__ inline i32x16 zero16(){
    i32x16 z;
    #pragma unroll
    for(int i=0;i<16;i++) z[i]=0;
    return z;
}

__device__ inline void gload16(const void* g, void* l){
    __builtin_amdgcn_global_load_lds((const __attribute__((address_space(1))) unsigned int*)g,
                                     (__attribute__((address_space(3))) unsigned int*)l, 16, 0, 0);
}

#define QSC 0.18033688011112042f   // 0.125 * log2(e)

// ---------------- fused quantization: weights (blocks 0..1023) + activations ----------------
__global__ __launch_bounds__(256) void quant_all(const float* __restrict__ x,
                                                 const float* __restrict__ w0,
                                                 const float* __restrict__ w1,
                                                 const float* __restrict__ w2,
                                                 const float* __restrict__ w3,
                                                 char* __restrict__ w8,
                                                 float* __restrict__ wsall,
                                                 char* __restrict__ xq8,
                                                 float* __restrict__ srow){
    int blk = blockIdx.x;
    int tid = threadIdx.x;
    if (blk < 1024){
        // ---- weight path (verified quant_w4) ----
        int widx = blk >> 8;
        const float* w = (widx==0)?w0 : (widx==1)?w1 : (widx==2)?w2 : w3;
        int gloc = (blk & 255)*32 + (tid >> 3);
        int j = tid & 7;
        const float* p = w + (size_t)gloc*GRP;
        float r = 0.f;
        #pragma unroll
        for(int i=0;i<16;i++) r += fabsf(p[8*i + j]);
        r += __shfl_xor(r, 1);
        r += __shfl_xor(r, 2);
        r += __shfl_xor(r, 4);
        float ws = r/(float)GRP + 1e-5f;
        if (j == 0) wsall[widx*8192 + gloc] = ws;
        int* q = (int*)(w8 + (size_t)widx*1048576 + (size_t)gloc*GRP);
        int i0 = j*16;
        #pragma unroll
        for(int c4=0;c4<4;c4++){
            float4 v = *(const float4*)(p + i0 + c4*4);
            int b0 = (int)fminf(fmaxf(rintf(v.x/ws),-1.f),1.f);
            int b1 = (int)fminf(fmaxf(rintf(v.y/ws),-1.f),1.f);
            int b2 = (int)fminf(fmaxf(rintf(v.z/ws),-1.f),1.f);
            int b3 = (int)fminf(fmaxf(rintf(v.w/ws),-1.f),1.f);
            q[j*4 + c4] = (b0&0xff) | ((b1&0xff)<<8) | ((b2&0xff)<<16) | ((b3&0xff)<<24);
        }
    } else {
        // ---- activation path (verified quant_x_i8) ----
        int row = blk - 1024;
        const float* p = x + (size_t)row*DIM;
        float4 v = *(const float4*)(p + tid*4);
        float m = fmaxf(fmaxf(fabsf(v.x),fabsf(v.y)), fmaxf(fabsf(v.z),fabsf(v.w)));
        m = wave_max(m);
        __shared__ float red[4];
        if ((tid&63)==0) red[tid>>6] = m;
        __syncthreads();
        m = fmaxf(fmaxf(red[0],red[1]), fmaxf(red[2],red[3]));
        float s = 127.f/(m+1e-5f);
        int a0 = (int)fminf(fmaxf(rintf(v.x*s),-128.f),127.f);
        int a1 = (int)fminf(fmaxf(rintf(v.y*s),-128.f),127.f);
        int a2 = (int)fminf(fmaxf(rintf(v.z*s),-128.f),127.f);
        int a3 = (int)fminf(fmaxf(rintf(v.w*s),-128.f),127.f);
        int pk = (a0&0xff) | ((a1&0xff)<<8) | ((a2&0xff)<<16) | ((a3&0xff)<<24);
        ((int*)xq8)[(size_t)row*256 + tid] = pk;
        if (tid==0) srow[row] = s;
    }
}

// ---------------- activation quantization (standalone, for attn output) ----------------
__global__ __launch_bounds__(256) void quant_x_i8(const float* __restrict__ x,
                                                  char* __restrict__ xq8,
                                                  float* __restrict__ srow){
    int row = blockIdx.x;
    int tid = threadIdx.x;
    const float* p = x + (size_t)row*DIM;
    float4 v = *(const float4*)(p + tid*4);
    float m = fmaxf(fmaxf(fabsf(v.x),fabsf(v.y)), fmaxf(fabsf(v.z),fabsf(v.w)));
    m = wave_max(m);
    __shared__ float red[4];
    if ((tid&63)==0) red[tid>>6] = m;
    __syncthreads();
    m = fmaxf(fmaxf(red[0],red[1]), fmaxf(red[2],red[3]));
    float s = 127.f/(m+1e-5f);
    int a0 = (int)fminf(fmaxf(rintf(v.x*s),-128.f),127.f);
    int a1 = (int)fminf(fmaxf(rintf(v.y*s),-128.f),127.f);
    int a2 = (int)fminf(fmaxf(rintf(v.z*s),-128.f),127.f);
    int a3 = (int)fminf(fmaxf(rintf(v.w*s),-128.f),127.f);
    int pk = (a0&0xff) | ((a1&0xff)<<8) | ((a2&0xff)<<16) | ((a3&0xff)<<24);
    ((int*)xq8)[(size_t)row*256 + tid] = pk;
    if (tid==0) srow[row] = s;
}

// ---------------- fused QKV int8 GEMM + RoPE + bf16 pack epilogue ----------------
// grid (24, 64): blockIdx.x = widx*8 + n-tile; 64x128 tile, dbuf over 8 groups.
// widx 0 -> Qh (row-order bf16, pre-scaled QSC, RoPE)
// widx 1 -> Kf (fragment-order bf16, RoPE)
// widx 2 -> Vf (fragment-order V^T bf16)
__global__ __launch_bounds__(256) void gemm_qkv(const char* __restrict__ A8,
                                                const char* __restrict__ w8all,
                                                const float* __restrict__ wsall,
                                                const float* __restrict__ srow,
                                                const float* __restrict__ cosb,
                                                const float* __restrict__ sinb,
                                                unsigned short* __restrict__ Qh,
                                                unsigned short* __restrict__ Kf,
                                                unsigned short* __restrict__ Vf){
    __shared__ __align__(16) char As[2][8192];
    __shared__ __align__(16) char Bs[2][16384];
    int nt = blockIdx.x;
    int widx = nt >> 3;
    int n0 = (nt & 7)*128;
    int m0 = blockIdx.y*64;
    const char* W8 = w8all + (size_t)widx*1048576;
    const float* wsb = wsall + widx*8192;

    int tid = threadIdx.x;
    int w = tid >> 6, lane = tid & 63;
    int wm = w & 1, wn = w >> 1;
    int l31 = lane & 31, lh = lane >> 5;

    float wsr[2][8];
    #pragma unroll
    for(int jt=0; jt<2; jt++){
        int col = n0 + (wn*2+jt)*32 + l31;
        float4 q0 = *(const float4*)(wsb + (size_t)col*8);
        float4 q1 = *(const float4*)(wsb + (size_t)col*8 + 4);
        wsr[jt][0]=q0.x; wsr[jt][1]=q0.y; wsr[jt][2]=q0.z; wsr[jt][3]=q0.w;
        wsr[jt][4]=q1.x; wsr[jt][5]=q1.y; wsr[jt][6]=q1.z; wsr[jt][7]=q1.w;
    }

    float facc[2][16];
    #pragma unroll
    for(int b=0;b<2;b++)
        #pragma unroll
        for(int r=0;r<16;r++) facc[b][r]=0.f;

    int row8 = lane >> 3;
    int scw  = (lane&7) ^ ((lane>>3)&7);
    const char* Ab = A8 + (size_t)m0*1024;
    const char* Bb = W8 + (size_t)n0*1024;

    {
        #pragma unroll
        for(int r=0;r<2;r++){
            int j = w*2 + r;
            gload16(Ab + (size_t)(j*8 + row8)*1024 + scw*16, As[0] + j*1024);
        }
        #pragma unroll
        for(int r=0;r<4;r++){
            int j = w*4 + r;
            gload16(Bb + (size_t)(j*8 + row8)*1024 + scw*16, Bs[0] + j*1024);
        }
    }

    #pragma unroll
    for(int g=0; g<8; g++){
        __syncthreads();
        if (g+1 < 8){
            int nb = (g+1)&1;
            #pragma unroll
            for(int r=0;r<2;r++){
                int j = w*2 + r;
                gload16(Ab + (size_t)(j*8 + row8)*1024 + (g+1)*128 + scw*16, As[nb] + j*1024);
            }
            #pragma unroll
            for(int r=0;r<4;r++){
                int j = w*4 + r;
                gload16(Bb + (size_t)(j*8 + row8)*1024 + (g+1)*128 + scw*16, Bs[nb] + j*1024);
            }
        }
        const char* Ac = As[g&1];
        const char* Bc = Bs[g&1];

        i32x16 iacc[2];
        iacc[0]=zero16(); iacc[1]=zero16();
        #pragma unroll
        for(int s=0; s<4; s++){
            int cw = s*2 + lh;
            int rlA = wm*32 + l31;
            i32x4 afr = *(const i32x4*)(Ac + (rlA*8 + (cw ^ (rlA&7)))*16);
            #pragma unroll
            for(int jt=0; jt<2; jt++){
                int rlB = (wn*2+jt)*32 + l31;
                i32x4 bfr = *(const i32x4*)(Bc + (rlB*8 + (cw ^ (rlB&7)))*16);
                iacc[jt] = __builtin_amdgcn_mfma_i32_32x32x32_i8(afr, bfr, iacc[jt], 0, 0, 0);
            }
        }
        #pragma unroll
        for(int jt=0; jt<2; jt++)
            #pragma unroll
            for(int r=0;r<16;r++)
                facc[jt][r] += (float)iacc[jt][r] * wsr[jt][g];
    }

    // ---- dequant by per-token scale ----
    float fin[2][16];
    #pragma unroll
    for(int r=0; r<16; r++){
        int rowl = wm*32 + (r&3) + 8*(r>>2) + 4*lh;
        float sv = srow[m0 + rowl];
        #pragma unroll
        for(int jt=0; jt<2; jt++) fin[jt][r] = facc[jt][r] / sv;
    }

    int kt = (m0 & (TT-1)) >> 6;     // block-uniform (m0 mult of 64)
    int bglob = m0 >> 11;            // batch index, block-uniform

    if (widx == 2){
        // ---- V: fragment-order V^T, ushort4 stores (4 consecutive tl) ----
        #pragma unroll
        for(int jt=0; jt<2; jt++){
            int col = n0 + (wn*2+jt)*32 + l31;
            int h = col >> 6, d = col & 63;
            int bh = bglob*NH + h;
            size_t tb = ((size_t)(bh*32 + kt))*512;
            int e = (d>>4)*128 + wm*64 + (d&15);   // + rb*16 below
            #pragma unroll
            for(int rb=0; rb<4; rb++){
                unsigned short s4[4];
                #pragma unroll
                for(int i=0;i<4;i++) s4[i] = f2bf(fin[jt][rb*4+i]);
                *(ushort2*)(Vf + (tb + e + rb*16)*8 + 4*lh)     = *(ushort2*)&s4[0];
                *(ushort2*)(Vf + (tb + e + rb*16)*8 + 4*lh + 2) = *(ushort2*)&s4[2];
            }
        }
    } else {
        // ---- Q or K: RoPE via lane pairing (col ^ 1 <-> lane l31 ^ 1) ----
        #pragma unroll
        for(int jt=0; jt<2; jt++){
            int col = n0 + (wn*2+jt)*32 + l31;
            int h = col >> 6, d = col & 63, p = d >> 1;
            int bh = bglob*NH + h;
            bool odd = (d & 1);
            #pragma unroll
            for(int r=0; r<16; r++){
                int rowl = wm*32 + (r&3) + 8*(r>>2) + 4*lh;
                int t = (m0 + rowl) & (TT-1);
                float c = cosb[t*32+p], s = sinb[t*32+p];
                float own = fin[jt][r];
                float part = __shfl_xor(own, 1);
                float e = odd ? part : own;
                float o = odd ? own  : part;
                float val = odd ? (e*s + o*c) : (e*c - o*s);
                if (widx == 0){
                    Qh[((size_t)bh*TT + t)*HD + d] = f2bf(val*QSC);
                } else {
                    int f = rowl >> 4, mm = rowl & 15;
                    size_t entry = ((size_t)(bh*32 + kt))*512 + f*128 + (p>>4)*64 + ((p>>2)&3)*16 + mm;
                    Kf[entry*8 + (p&3)*2 + (d&1)] = f2bf(val);
                }
            }
        }
    }
}

// ---------------- int8 MFMA GEMM (output projection, verified R5) ----------------
__global__ __launch_bounds__(256) void gemm_i8(const char* __restrict__ A8,
                                               const char* __restrict__ W8,
                                               const float* __restrict__ wsb,
                                               const float* __restrict__ srow,
                                               float* __restrict__ C){
    __shared__ __align__(16) char As[2][8192];
    __shared__ __align__(16) char Bs[2][16384];
    int tid = threadIdx.x;
    int w = tid >> 6, lane = tid & 63;
    int wm = w & 1, wn = w >> 1;
    int m0 = blockIdx.y*64, n0 = blockIdx.x*128;
    int l31 = lane & 31, lh = lane >> 5;

    float wsr[2][8];
    #pragma unroll
    for(int jt=0; jt<2; jt++){
        int col = n0 + (wn*2+jt)*32 + l31;
        float4 q0 = *(const float4*)(wsb + (size_t)col*8);
        float4 q1 = *(const float4*)(wsb + (size_t)col*8 + 4);
        wsr[jt][0]=q0.x; wsr[jt][1]=q0.y; wsr[jt][2]=q0.z; wsr[jt][3]=q0.w;
        wsr[jt][4]=q1.x; wsr[jt][5]=q1.y; wsr[jt][6]=q1.z; wsr[jt][7]=q1.w;
    }

    float facc[2][16];
    #pragma unroll
    for(int b=0;b<2;b++)
        #pragma unroll
        for(int r=0;r<16;r++) facc[b][r]=0.f;

    int row8 = lane >> 3;
    int scw  = (lane&7) ^ ((lane>>3)&7);
    const char* Ab = A8 + (size_t)m0*1024;
    const char* Bb = W8 + (size_t)n0*1024;

    {
        #pragma unroll
        for(int r=0;r<2;r++){
            int j = w*2 + r;
            gload16(Ab + (size_t)(j*8 + row8)*1024 + scw*16, As[0] + j*1024);
        }
        #pragma unroll
        for(int r=0;r<4;r++){
            int j = w*4 + r;
            gload16(Bb + (size_t)(j*8 + row8)*1024 + scw*16, Bs[0] + j*1024);
        }
    }

    #pragma unroll
    for(int g=0; g<8; g++){
        __syncthreads();
        if (g+1 < 8){
            int nb = (g+1)&1;
            #pragma unroll
            for(int r=0;r<2;r++){
                int j = w*2 + r;
                gload16(Ab + (size_t)(j*8 + row8)*1024 + (g+1)*128 + scw*16, As[nb] + j*1024);
            }
            #pragma unroll
            for(int r=0;r<4;r++){
                int j = w*4 + r;
                gload16(Bb + (size_t)(j*8 + row8)*1024 + (g+1)*128 + scw*16, Bs[nb] + j*1024);
            }
        }
        const char* Ac = As[g&1];
        const char* Bc = Bs[g&1];

        i32x16 iacc[2];
        iacc[0]=zero16(); iacc[1]=zero16();
        #pragma unroll
        for(int s=0; s<4; s++){
            int cw = s*2 + lh;
            int rlA = wm*32 + l31;
            i32x4 afr = *(const i32x4*)(Ac + (rlA*8 + (cw ^ (rlA&7)))*16);
            #pragma unroll
            for(int jt=0; jt<2; jt++){
                int rlB = (wn*2+jt)*32 + l31;
                i32x4 bfr = *(const i32x4*)(Bc + (rlB*8 + (cw ^ (rlB&7)))*16);
                iacc[jt] = __builtin_amdgcn_mfma_i32_32x32x32_i8(afr, bfr, iacc[jt], 0, 0, 0);
            }
        }
        #pragma unroll
        for(int jt=0; jt<2; jt++)
            #pragma unroll
            for(int r=0;r<16;r++)
                facc[jt][r] += (float)iacc[jt][r] * wsr[jt][g];
    }

    #pragma unroll
    for(int r=0; r<16; r++){
        int rowl = wm*32 + (r&3) + 8*(r>>2) + 4*lh;
        float sv = srow[m0 + rowl];
        #pragma unroll
        for(int jt=0; jt<2; jt++){
            int col = n0 + (wn*2+jt)*32 + l31;
            C[(size_t)(m0+rowl)*DIM + col] = facc[jt][r] / sv;
        }
    }
}

// ---------------- MFMA flash attention v4: split-K for qt>=16 ----------------
// grid 1536: blk -> bh = blk&31, s = blk>>5 (0..47).
//   s<32 : qt=31-s, part 0: keys [0, h1) where h1 = qt<16 ? qt+1 : (qt+1)/2
//   s>=32: qt=63-s (16..31), part 1: keys [h1, qt+1)
// Unsplit (qt<16) writes ao directly; split parts write (m,l,O) partials.
__global__ __launch_bounds__(256) void attn_mfma4(const unsigned short* __restrict__ Qh,
                                                  const unsigned short* __restrict__ Kf,
                                                  const unsigned short* __restrict__ Vf,
                                                  float* __restrict__ ao,
                                                  float* __restrict__ Po,
                                                  float* __restrict__ Pm,
                                                  float* __restrict__ Pl){
    __shared__ s16x8 Kbuf[2][512];
    __shared__ s16x8 Vbuf[2][512];
    int blk = blockIdx.x;
    int bh = blk & 31;
    int s_ = blk >> 5;
    int part = (s_ >= 32);
    int qt = part ? (63 - s_) : (31 - s_);
    int h1 = (qt < 16) ? (qt + 1) : ((qt + 1) >> 1);
    int k0 = part ? h1 : 0;
    int k1 = part ? (qt + 1) : h1;
    int n = k1 - k0;
    int b  = bh >> 4;
    int tid = threadIdx.x;
    int w = tid >> 6, lane = tid & 63;
    int m = lane & 15, g = lane >> 4;
    int q = qt*64 + w*16 + m;

    const unsigned short* Qhead = Qh + (size_t)bh*TT*HD;
    const s16x8* Kbase = (const s16x8*)(Kf + (size_t)bh*32*4096);
    const s16x8* Vbase = (const s16x8*)(Vf + (size_t)bh*32*4096);

    s16x8 Qf0 = *(const s16x8*)(Qhead + (size_t)q*HD + g*8);
    s16x8 Qf1 = *(const s16x8*)(Qhead + (size_t)q*HD + g*8 + 32);

    f32x4 Of[4] = {f32x4{0,0,0,0}, f32x4{0,0,0,0}, f32x4{0,0,0,0}, f32x4{0,0,0,0}};
    float mrow = -1e30f, lrow = 0.f;

    // prologue: stage tile k0 into buffer 0
    #pragma unroll
    for(int r=0;r<2;r++){
        gload16((const char*)(Kbase + (size_t)k0*512) + ((r*4 + w)*64 + lane)*16, (char*)Kbuf[0] + (r*4 + w)*1024);
        gload16((const char*)(Vbase + (size_t)k0*512) + ((r*4 + w)*64 + lane)*16, (char*)Vbuf[0] + (r*4 + w)*1024);
    }

    for(int i=0; i<n; i++){
        int kt = k0 + i;
        __syncthreads();
        if (i+1 < n){
            int nb = (i+1)&1;
            const char* kg = (const char*)(Kbase + (size_t)(kt+1)*512);
            const char* vg = (const char*)(Vbase + (size_t)(kt+1)*512);
            #pragma unroll
            for(int r=0;r<2;r++){
                gload16(kg + ((r*4 + w)*64 + lane)*16, (char*)Kbuf[nb] + (r*4 + w)*1024);
                gload16(vg + ((r*4 + w)*64 + lane)*16, (char*)Vbuf[nb] + (r*4 + w)*1024);
            }
        }
        const s16x8* Kc = Kbuf[i&1];
        const s16x8* Vc = Vbuf[i&1];

        f32x4 S[4];
        #pragma unroll
        for(int f=0; f<4; f++){
            s16x8 kk0 = Kc[(f*2+0)*64 + lane];
            s16x8 kk1 = Kc[(f*2+1)*64 + lane];
            f32x4 acc = {0,0,0,0};
            acc = __builtin_amdgcn_mfma_f32_16x16x32_bf16(kk0, Qf0, acc, 0, 0, 0);
            acc = __builtin_amdgcn_mfma_f32_16x16x32_bf16(kk1, Qf1, acc, 0, 0, 0);
            S[f] = acc;
        }

        float p[4][4];
        float mloc = -1e30f;
        if (kt == qt){
            #pragma unroll
            for(int f=0; f<4; f++)
                #pragma unroll
                for(int r=0; r<4; r++){
                    int key = 16*f + 4*g + r;
                    float sv = (qt*64 + key > q) ? -1e30f : S[f][r];
                    p[f][r] = sv;
                    mloc = fmaxf(mloc, sv);
                }
        } else {
            #pragma unroll
            for(int f=0; f<4; f++)
                #pragma unroll
                for(int r=0; r<4; r++){
                    p[f][r] = S[f][r];
                    mloc = fmaxf(mloc, S[f][r]);
                }
        }
        mloc = fmaxf(mloc, __shfl_xor(mloc, 16));
        mloc = fmaxf(mloc, __shfl_xor(mloc, 32));
        float mn = fmaxf(mrow, mloc);
        float alpha = fexp2(mrow - mn);
        float ps = 0.f;
        #pragma unroll
        for(int f=0; f<4; f++)
            #pragma unroll
            for(int r=0; r<4; r++){
                float e = fexp2(p[f][r] - mn);
                p[f][r] = e;
                ps += e;
            }
        ps += __shfl_xor(ps, 16);
        ps += __shfl_xor(ps, 32);
        lrow = lrow*alpha + ps;
        mrow = mn;

        #pragma unroll
        for(int f2=0; f2<4; f2++)
            #pragma unroll
            for(int r=0; r<4; r++) Of[f2][r] *= alpha;

        unsigned pp0[4], pp1[4];
        #pragma unroll
        for(int f=0; f<4; f++){
            pp0[f] = pk2(p[f][0], p[f][1]);
            pp1[f] = pk2(p[f][2], p[f][3]);
        }

        int src0 = m + 16*(2*(g&1));
        int src1 = src0 + 16;
        bool hi = (g >= 2);
        #pragma unroll
        for(int c=0; c<2; c++){
            unsigned a0 = (unsigned)__shfl((int)pp0[2*c],   src0);
            unsigned a1 = (unsigned)__shfl((int)pp0[2*c+1], src0);
            unsigned b0 = hi ? a1 : a0;
            unsigned a2 = (unsigned)__shfl((int)pp1[2*c],   src0);
            unsigned a3 = (unsigned)__shfl((int)pp1[2*c+1], src0);
            unsigned b1 = hi ? a3 : a2;
            unsigned a4 = (unsigned)__shfl((int)pp0[2*c],   src1);
            unsigned a5 = (unsigned)__shfl((int)pp0[2*c+1], src1);
            unsigned b2 = hi ? a5 : a4;
            unsigned a6 = (unsigned)__shfl((int)pp1[2*c],   src1);
            unsigned a7 = (unsigned)__shfl((int)pp1[2*c+1], src1);
            unsigned b3 = hi ? a7 : a6;
            union { unsigned u[4]; s16x8 v; } Bf;
            Bf.u[0]=b0; Bf.u[1]=b1; Bf.u[2]=b2; Bf.u[3]=b3;
            #pragma unroll
            for(int f2=0; f2<4; f2++){
                s16x8 vf = Vc[(f2*2+c)*64 + lane];
                Of[f2] = __builtin_amdgcn_mfma_f32_16x16x32_bf16(vf, Bf.v, Of[f2], 0, 0, 0);
            }
        }
    }

    if (qt < 16){
        float invl = 1.0f / lrow;
        size_t obase = (size_t)(b*TT + q)*DIM + (bh & 15)*HD;
        #pragma unroll
        for(int f2=0; f2<4; f2++)
            #pragma unroll
            for(int r=0; r<4; r++)
                ao[obase + 16*f2 + 4*g + r] = Of[f2][r]*invl;
    } else {
        int si = (bh*16 + (qt-16))*2 + part;
        float* Ob = Po + (size_t)si*4096 + (w*16 + m)*64;
        #pragma unroll
        for(int f2=0; f2<4; f2++)
            #pragma unroll
            for(int r=0; r<4; r++)
                Ob[16*f2 + 4*g + r] = Of[f2][r];
        if (g == 0){
            Pm[si*64 + w*16 + m] = mrow;
            Pl[si*64 + w*16 + m] = lrow;
        }
    }
}

// ---------------- merge split-K partials ----------------
// grid 512: blk -> bh = blk>>4, qt = 16 + (blk&15). 256 threads, 16 elems each.
__global__ __launch_bounds__(256) void attn_merge(const float* __restrict__ Po,
                                                  const float* __restrict__ Pm,
                                                  const float* __restrict__ Pl,
                                                  float* __restrict__ ao){
    int blk = blockIdx.x;
    int bh = blk >> 4;
    int qti = blk & 15;
    int qt = 16 + qti;
    int b = bh >> 4, h = bh & 15;
    int tid = threadIdx.x;
    int row = tid >> 2;
    int d0 = (tid & 3)*16;
    int si = (bh*16 + qti)*2;
    float m1 = Pm[si*64 + row],     l1 = Pl[si*64 + row];
    float m2 = Pm[(si+1)*64 + row], l2 = Pl[(si+1)*64 + row];
    float mm = fmaxf(m1, m2);
    float w1 = fexp2(m1 - mm), w2 = fexp2(m2 - mm);
    float inv = 1.0f / (w1*l1 + w2*l2);
    const float* O1 = Po + (size_t)si*4096 + row*64 + d0;
    const float* O2 = Po + (size_t)(si+1)*4096 + row*64 + d0;
    int q = qt*64 + row;
    float* outp = ao + (size_t)(b*TT + q)*DIM + h*HD + d0;
    #pragma unroll
    for(int c=0; c<4; c++){
        float4 v1 = *(const float4*)(O1 + c*4);
        float4 v2 = *(const float4*)(O2 + c*4);
        float4 o;
        o.x = (v1.x*w1 + v2.x*w2)*inv;
        o.y = (v1.y*w1 + v2.y*w2)*inv;
        o.z = (v1.z*w1 + v2.z*w2)*inv;
        o.w = (v1.w*w1 + v2.w*w2)*inv;
        *(float4*)(outp + c*4) = o;
    }
}

// ---------------- launch ----------------
extern "C" void kernel_launch(void* const* d_in, const int* in_sizes, int n_in,
                              void* d_out, int out_size, void* d_ws, size_t ws_size,
                              hipStream_t stream){
    const float* x    = (const float*)d_in[0];
    const float* cosb = (const float*)d_in[1];
    const float* sinb = (const float*)d_in[2];
    const float* wq_w = (const float*)d_in[3];
    const float* wk_w = (const float*)d_in[4];
    const float* wv_w = (const float*)d_in[5];
    const float* wo_w = (const float*)d_in[6];
    float* out = (float*)d_out;

    char* cw = (char*)d_ws;
    const size_t MB = 1048576;
    char*  w8all = cw;                             // [0,4MB)
    float* wsall = (float*)(cw + 4*MB);            // 128 KB
    float* srow1 = (float*)(cw + 4*MB + 131072);   // 16 KB
    float* srow2 = (float*)(cw + 4*MB + 147456);   // 16 KB
    char*  xq8   = cw + 5*MB;                      // [5,9MB)
    char*  xq8_2 = cw + 9*MB;                      // [9,13MB)
    unsigned short* Qh = (unsigned short*)(cw + 13*MB);  // [13,21MB)
    unsigned short* Kf = (unsigned short*)(cw + 21*MB);  // [21,29MB)
    unsigned short* Vf = (unsigned short*)(cw + 29*MB);  // [29,37MB)
    float* ao    = (float*)(cw + 37*MB);           // [37,53MB)
    float* Po    = (float*)(cw + 53*MB);           // 16.78 MB -> [53,70MB)
    float* Pm    = (float*)(cw + 70*MB);           // 256 KB
    float* Pl    = (float*)(cw + 70*MB + 262144);  // 256 KB

    quant_all<<<1024 + MROWS, 256, 0, stream>>>(x, wq_w, wk_w, wv_w, wo_w,
                                                w8all, wsall, xq8, srow1);

    gemm_qkv<<<dim3(24, MROWS/64), 256, 0, stream>>>(xq8, w8all, wsall, srow1,
                                                     cosb, sinb, Qh, Kf, Vf);

    attn_mfma4<<<1536, 256, 0, stream>>>(Qh, Kf, Vf, ao, Po, Pm, Pl);
    attn_merge<<<512, 256, 0, stream>>>(Po, Pm, Pl, ao);

    quant_x_i8<<<MROWS, 256, 0, stream>>>(ao, xq8_2, srow2);
    gemm_i8<<<dim3(DIM/128, MROWS/64), 256, 0, stream>>>(xq8_2, w8all + 3*MB,
                                                         wsall + 3*8192, srow2, out);
}

// Round 7
// 206.147 us; speedup vs baseline: 1.2707x; 1.2707x over previous
//
#include <hip/hip_runtime.h>
#include <math.h>

#define DIM   1024
#define NH    16
#define HD    64
#define GRP   128
#define BB    2
#define TT    2048
#define MROWS (BB*TT)   // 4096

typedef __attribute__((ext_vector_type(8))) short s16x8;
typedef __attribute__((ext_vector_type(4))) float f32x4;
typedef __attribute__((ext_vector_type(4))) int   i32x4;
typedef __attribute__((ext_vector_type(16))) int  i32x16;

__device__ inline float wave_max(float v){
    for(int off=32; off; off>>=1) v = fmaxf(v, __shfl_xor(v, off));
    return v;
}

__device__ inline unsigned short f2bf(float x){
    union { float f; unsigned u; } v; v.f = x;
    unsigned r = v.u + 0x7fffu + ((v.u >> 16) & 1u);
    return (unsigned short)(r >> 16);
}

#if __has_builtin(__builtin_amdgcn_cvt_pk_bf16_f32)
typedef __bf16 bf16x2 __attribute__((ext_vector_type(2)));
__device__ inline unsigned pk2(float a, float b){
    union { bf16x2 v; unsigned u; } c;
    c.v = __builtin_amdgcn_cvt_pk_bf16_f32(a, b);
    return c.u;
}
#else
__device__ inline unsigned pk2(float a, float b){
    return (unsigned)f2bf(a) | ((unsigned)f2bf(b) << 16);
}
#endif

#if __has_builtin(__builtin_amdgcn_exp2f)
__device__ inline float fexp2(float x){ return __builtin_amdgcn_exp2f(x); }
#else
__device__ inline float fexp2(float x){ return exp2f(x); }
#endif

__device__ inline i32x16 zero16(){
    i32x16 z;
    #pragma unroll
    for(int i=0;i<16;i++) z[i]=0;
    return z;
}

__device__ inline void gload16(const void* g, void* l){
    __builtin_amdgcn_global_load_lds((const __attribute__((address_space(1))) unsigned int*)g,
                                     (__attribute__((address_space(3))) unsigned int*)l, 16, 0, 0);
}

#define QSC 0.18033688011112042f   // 0.125 * log2(e)

// ---------------- fused quantization: weights (blocks 0..1023) + activations ----------------
__global__ __launch_bounds__(256) void quant_all(const float* __restrict__ x,
                                                 const float* __restrict__ w0,
                                                 const float* __restrict__ w1,
                                                 const float* __restrict__ w2,
                                                 const float* __restrict__ w3,
                                                 char* __restrict__ w8,
                                                 float* __restrict__ wsall,
                                                 char* __restrict__ xq8,
                                                 float* __restrict__ srow){
    int blk = blockIdx.x;
    int tid = threadIdx.x;
    if (blk < 1024){
        int widx = blk >> 8;
        const float* w = (widx==0)?w0 : (widx==1)?w1 : (widx==2)?w2 : w3;
        int gloc = (blk & 255)*32 + (tid >> 3);
        int j = tid & 7;
        const float* p = w + (size_t)gloc*GRP;
        float r = 0.f;
        #pragma unroll
        for(int i=0;i<16;i++) r += fabsf(p[8*i + j]);
        r += __shfl_xor(r, 1);
        r += __shfl_xor(r, 2);
        r += __shfl_xor(r, 4);
        float ws = r/(float)GRP + 1e-5f;
        if (j == 0) wsall[widx*8192 + gloc] = ws;
        int* q = (int*)(w8 + (size_t)widx*1048576 + (size_t)gloc*GRP);
        int i0 = j*16;
        #pragma unroll
        for(int c4=0;c4<4;c4++){
            float4 v = *(const float4*)(p + i0 + c4*4);
            int b0 = (int)fminf(fmaxf(rintf(v.x/ws),-1.f),1.f);
            int b1 = (int)fminf(fmaxf(rintf(v.y/ws),-1.f),1.f);
            int b2 = (int)fminf(fmaxf(rintf(v.z/ws),-1.f),1.f);
            int b3 = (int)fminf(fmaxf(rintf(v.w/ws),-1.f),1.f);
            q[j*4 + c4] = (b0&0xff) | ((b1&0xff)<<8) | ((b2&0xff)<<16) | ((b3&0xff)<<24);
        }
    } else {
        int row = blk - 1024;
        const float* p = x + (size_t)row*DIM;
        float4 v = *(const float4*)(p + tid*4);
        float m = fmaxf(fmaxf(fabsf(v.x),fabsf(v.y)), fmaxf(fabsf(v.z),fabsf(v.w)));
        m = wave_max(m);
        __shared__ float red[4];
        if ((tid&63)==0) red[tid>>6] = m;
        __syncthreads();
        m = fmaxf(fmaxf(red[0],red[1]), fmaxf(red[2],red[3]));
        float s = 127.f/(m+1e-5f);
        int a0 = (int)fminf(fmaxf(rintf(v.x*s),-128.f),127.f);
        int a1 = (int)fminf(fmaxf(rintf(v.y*s),-128.f),127.f);
        int a2 = (int)fminf(fmaxf(rintf(v.z*s),-128.f),127.f);
        int a3 = (int)fminf(fmaxf(rintf(v.w*s),-128.f),127.f);
        int pk = (a0&0xff) | ((a1&0xff)<<8) | ((a2&0xff)<<16) | ((a3&0xff)<<24);
        ((int*)xq8)[(size_t)row*256 + tid] = pk;
        if (tid==0) srow[row] = s;
    }
}

// ---------------- activation quantization (standalone, for attn output) ----------------
__global__ __launch_bounds__(256) void quant_x_i8(const float* __restrict__ x,
                                                  char* __restrict__ xq8,
                                                  float* __restrict__ srow){
    int row = blockIdx.x;
    int tid = threadIdx.x;
    const float* p = x + (size_t)row*DIM;
    float4 v = *(const float4*)(p + tid*4);
    float m = fmaxf(fmaxf(fabsf(v.x),fabsf(v.y)), fmaxf(fabsf(v.z),fabsf(v.w)));
    m = wave_max(m);
    __shared__ float red[4];
    if ((tid&63)==0) red[tid>>6] = m;
    __syncthreads();
    m = fmaxf(fmaxf(red[0],red[1]), fmaxf(red[2],red[3]));
    float s = 127.f/(m+1e-5f);
    int a0 = (int)fminf(fmaxf(rintf(v.x*s),-128.f),127.f);
    int a1 = (int)fminf(fmaxf(rintf(v.y*s),-128.f),127.f);
    int a2 = (int)fminf(fmaxf(rintf(v.z*s),-128.f),127.f);
    int a3 = (int)fminf(fmaxf(rintf(v.w*s),-128.f),127.f);
    int pk = (a0&0xff) | ((a1&0xff)<<8) | ((a2&0xff)<<16) | ((a3&0xff)<<24);
    ((int*)xq8)[(size_t)row*256 + tid] = pk;
    if (tid==0) srow[row] = s;
}

// ---------------- fused QKV int8 GEMM + LDS-staged RoPE/bf16 pack epilogue ----------------
// grid (24, 64): blockIdx.x = widx*8 + n-tile; 64x128 tile, dbuf over 8 groups.
// After the K-loop the fp32 result is staged in LDS (64 x 132-padded), then a
// re-partitioned pack phase writes Qh / Kf / Vf with contiguous 16B stores.
__global__ __launch_bounds__(256) void gemm_qkv(const char* __restrict__ A8,
                                                const char* __restrict__ w8all,
                                                const float* __restrict__ wsall,
                                                const float* __restrict__ srow,
                                                const float* __restrict__ cosb,
                                                const float* __restrict__ sinb,
                                                unsigned short* __restrict__ Qh,
                                                unsigned short* __restrict__ Kf,
                                                unsigned short* __restrict__ Vf){
    __shared__ __align__(16) char smem[49152];   // staging dbuf, then fp32 tile
    char* AsB[2] = { smem,         smem + 8192  };
    char* BsB[2] = { smem + 16384, smem + 32768 };
    float* T = (float*)smem;                     // 64 x 132 fp32 = 33792 B

    int nt = blockIdx.x;
    int widx = nt >> 3;
    int n0 = (nt & 7)*128;
    int m0 = blockIdx.y*64;
    const char* W8 = w8all + (size_t)widx*1048576;
    const float* wsb = wsall + widx*8192;

    int tid = threadIdx.x;
    int w = tid >> 6, lane = tid & 63;
    int wm = w & 1, wn = w >> 1;
    int l31 = lane & 31, lh = lane >> 5;

    float wsr[2][8];
    #pragma unroll
    for(int jt=0; jt<2; jt++){
        int col = n0 + (wn*2+jt)*32 + l31;
        float4 q0 = *(const float4*)(wsb + (size_t)col*8);
        float4 q1 = *(const float4*)(wsb + (size_t)col*8 + 4);
        wsr[jt][0]=q0.x; wsr[jt][1]=q0.y; wsr[jt][2]=q0.z; wsr[jt][3]=q0.w;
        wsr[jt][4]=q1.x; wsr[jt][5]=q1.y; wsr[jt][6]=q1.z; wsr[jt][7]=q1.w;
    }

    float facc[2][16];
    #pragma unroll
    for(int b=0;b<2;b++)
        #pragma unroll
        for(int r=0;r<16;r++) facc[b][r]=0.f;

    int row8 = lane >> 3;
    int scw  = (lane&7) ^ ((lane>>3)&7);
    const char* Ab = A8 + (size_t)m0*1024;
    const char* Bb = W8 + (size_t)n0*1024;

    {
        #pragma unroll
        for(int r=0;r<2;r++){
            int j = w*2 + r;
            gload16(Ab + (size_t)(j*8 + row8)*1024 + scw*16, AsB[0] + j*1024);
        }
        #pragma unroll
        for(int r=0;r<4;r++){
            int j = w*4 + r;
            gload16(Bb + (size_t)(j*8 + row8)*1024 + scw*16, BsB[0] + j*1024);
        }
    }

    #pragma unroll
    for(int g=0; g<8; g++){
        __syncthreads();
        if (g+1 < 8){
            int nb = (g+1)&1;
            #pragma unroll
            for(int r=0;r<2;r++){
                int j = w*2 + r;
                gload16(Ab + (size_t)(j*8 + row8)*1024 + (g+1)*128 + scw*16, AsB[nb] + j*1024);
            }
            #pragma unroll
            for(int r=0;r<4;r++){
                int j = w*4 + r;
                gload16(Bb + (size_t)(j*8 + row8)*1024 + (g+1)*128 + scw*16, BsB[nb] + j*1024);
            }
        }
        const char* Ac = AsB[g&1];
        const char* Bc = BsB[g&1];

        i32x16 iacc[2];
        iacc[0]=zero16(); iacc[1]=zero16();
        #pragma unroll
        for(int s=0; s<4; s++){
            int cw = s*2 + lh;
            int rlA = wm*32 + l31;
            i32x4 afr = *(const i32x4*)(Ac + (rlA*8 + (cw ^ (rlA&7)))*16);
            #pragma unroll
            for(int jt=0; jt<2; jt++){
                int rlB = (wn*2+jt)*32 + l31;
                i32x4 bfr = *(const i32x4*)(Bc + (rlB*8 + (cw ^ (rlB&7)))*16);
                iacc[jt] = __builtin_amdgcn_mfma_i32_32x32x32_i8(afr, bfr, iacc[jt], 0, 0, 0);
            }
        }
        #pragma unroll
        for(int jt=0; jt<2; jt++)
            #pragma unroll
            for(int r=0;r<16;r++)
                facc[jt][r] += (float)iacc[jt][r] * wsr[jt][g];
    }

    // ---- dequant into LDS fp32 tile ----
    __syncthreads();   // all waves done reading staging buffers
    #pragma unroll
    for(int r=0; r<16; r++){
        int rowl = wm*32 + (r&3) + 8*(r>>2) + 4*lh;
        float sv = srow[m0 + rowl];
        #pragma unroll
        for(int jt=0; jt<2; jt++){
            int col = (wn*2+jt)*32 + l31;
            T[rowl*132 + col] = facc[jt][r] / sv;
        }
    }
    __syncthreads();

    int kt = (m0 & (TT-1)) >> 6;     // block-uniform key tile
    int bglob = m0 >> 11;            // batch, block-uniform
    int h0 = n0 >> 6;                // first of the 2 heads this block covers

    if (widx == 0){
        // ---- Q: row-order bf16, RoPE + QSC. thread = (row, 32-col chunk) ----
        int row = tid & 63, chunk = tid >> 6;
        int t = (m0 + row) & (TT-1);
        const float* Tr = T + row*132 + chunk*32;
        int colbase = n0 + chunk*32;
        int h = colbase >> 6;
        int d0 = colbase & 63;           // 0 or 32
        int bh = bglob*NH + h;
        unsigned short* dst = Qh + ((size_t)bh*TT + t)*HD + d0;
        int p0 = d0 >> 1;
        __align__(16) unsigned short ob[32];
        #pragma unroll
        for(int pp=0; pp<16; pp++){
            float c = cosb[t*32 + p0 + pp], s = sinb[t*32 + p0 + pp];
            float e = Tr[2*pp], o = Tr[2*pp+1];
            ob[2*pp]   = f2bf((e*c - o*s)*QSC);
            ob[2*pp+1] = f2bf((e*s + o*c)*QSC);
        }
        #pragma unroll
        for(int c4=0;c4<4;c4++)
            *(s16x8*)(dst + c4*8) = *(s16x8*)(ob + c4*8);
    } else if (widx == 1){
        // ---- K: fragment-order bf16, RoPE. thread handles 4 x 16B entries ----
        #pragma unroll
        for(int i=0;i<4;i++){
            int e = tid + 256*i;
            int h = e >> 9, e2 = e & 511;
            int f = e2 >> 7, cc = (e2 >> 6)&1, gg = (e2 >> 4)&3, mm = e2 & 15;
            int row = 16*f + mm;
            int t = (m0 + row) & (TT-1);
            int d0 = 8*gg + 32*cc;
            const float* Tr = T + row*132 + h*64 + d0;
            int p0 = d0 >> 1;
            __align__(16) unsigned short ob[8];
            #pragma unroll
            for(int pp=0;pp<4;pp++){
                float c = cosb[t*32 + p0 + pp], s = sinb[t*32 + p0 + pp];
                float ev = Tr[2*pp], ov = Tr[2*pp+1];
                ob[2*pp]   = f2bf(ev*c - ov*s);
                ob[2*pp+1] = f2bf(ev*s + ov*c);
            }
            int bh = bglob*NH + h0 + h;
            size_t entry = ((size_t)(bh*32 + kt))*512 + e2;
            *(s16x8*)(Kf + entry*8) = *(s16x8*)ob;
        }
    } else {
        // ---- V: fragment-order V^T bf16. entry holds 8 consecutive tokens ----
        #pragma unroll
        for(int i=0;i<4;i++){
            int e = tid + 256*i;
            int h = e >> 9, e2 = e & 511;
            int f = e2 >> 7, cc = (e2 >> 6)&1, gg = (e2 >> 4)&3, mm = e2 & 15;
            int dv = 16*f + mm;
            int tl0 = 8*gg + 32*cc;
            __align__(16) unsigned short ob[8];
            #pragma unroll
            for(int j=0;j<8;j++)
                ob[j] = f2bf(T[(tl0+j)*132 + h*64 + dv]);
            int bh = bglob*NH + h0 + h;
            size_t entry = ((size_t)(bh*32 + kt))*512 + e2;
            *(s16x8*)(Vf + entry*8) = *(s16x8*)ob;
        }
    }
}

// ---------------- int8 MFMA GEMM (output projection, verified R5) ----------------
__global__ __launch_bounds__(256) void gemm_i8(const char* __restrict__ A8,
                                               const char* __restrict__ W8,
                                               const float* __restrict__ wsb,
                                               const float* __restrict__ srow,
                                               float* __restrict__ C){
    __shared__ __align__(16) char As[2][8192];
    __shared__ __align__(16) char Bs[2][16384];
    int tid = threadIdx.x;
    int w = tid >> 6, lane = tid & 63;
    int wm = w & 1, wn = w >> 1;
    int m0 = blockIdx.y*64, n0 = blockIdx.x*128;
    int l31 = lane & 31, lh = lane >> 5;

    float wsr[2][8];
    #pragma unroll
    for(int jt=0; jt<2; jt++){
        int col = n0 + (wn*2+jt)*32 + l31;
        float4 q0 = *(const float4*)(wsb + (size_t)col*8);
        float4 q1 = *(const float4*)(wsb + (size_t)col*8 + 4);
        wsr[jt][0]=q0.x; wsr[jt][1]=q0.y; wsr[jt][2]=q0.z; wsr[jt][3]=q0.w;
        wsr[jt][4]=q1.x; wsr[jt][5]=q1.y; wsr[jt][6]=q1.z; wsr[jt][7]=q1.w;
    }

    float facc[2][16];
    #pragma unroll
    for(int b=0;b<2;b++)
        #pragma unroll
        for(int r=0;r<16;r++) facc[b][r]=0.f;

    int row8 = lane >> 3;
    int scw  = (lane&7) ^ ((lane>>3)&7);
    const char* Ab = A8 + (size_t)m0*1024;
    const char* Bb = W8 + (size_t)n0*1024;

    {
        #pragma unroll
        for(int r=0;r<2;r++){
            int j = w*2 + r;
            gload16(Ab + (size_t)(j*8 + row8)*1024 + scw*16, As[0] + j*1024);
        }
        #pragma unroll
        for(int r=0;r<4;r++){
            int j = w*4 + r;
            gload16(Bb + (size_t)(j*8 + row8)*1024 + scw*16, Bs[0] + j*1024);
        }
    }

    #pragma unroll
    for(int g=0; g<8; g++){
        __syncthreads();
        if (g+1 < 8){
            int nb = (g+1)&1;
            #pragma unroll
            for(int r=0;r<2;r++){
                int j = w*2 + r;
                gload16(Ab + (size_t)(j*8 + row8)*1024 + (g+1)*128 + scw*16, As[nb] + j*1024);
            }
            #pragma unroll
            for(int r=0;r<4;r++){
                int j = w*4 + r;
                gload16(Bb + (size_t)(j*8 + row8)*1024 + (g+1)*128 + scw*16, Bs[nb] + j*1024);
            }
        }
        const char* Ac = As[g&1];
        const char* Bc = Bs[g&1];

        i32x16 iacc[2];
        iacc[0]=zero16(); iacc[1]=zero16();
        #pragma unroll
        for(int s=0; s<4; s++){
            int cw = s*2 + lh;
            int rlA = wm*32 + l31;
            i32x4 afr = *(const i32x4*)(Ac + (rlA*8 + (cw ^ (rlA&7)))*16);
            #pragma unroll
            for(int jt=0; jt<2; jt++){
                int rlB = (wn*2+jt)*32 + l31;
                i32x4 bfr = *(const i32x4*)(Bc + (rlB*8 + (cw ^ (rlB&7)))*16);
                iacc[jt] = __builtin_amdgcn_mfma_i32_32x32x32_i8(afr, bfr, iacc[jt], 0, 0, 0);
            }
        }
        #pragma unroll
        for(int jt=0; jt<2; jt++)
            #pragma unroll
            for(int r=0;r<16;r++)
                facc[jt][r] += (float)iacc[jt][r] * wsr[jt][g];
    }

    #pragma unroll
    for(int r=0; r<16; r++){
        int rowl = wm*32 + (r&3) + 8*(r>>2) + 4*lh;
        float sv = srow[m0 + rowl];
        #pragma unroll
        for(int jt=0; jt<2; jt++){
            int col = n0 + (wn*2+jt)*32 + l31;
            C[(size_t)(m0+rowl)*DIM + col] = facc[jt][r] / sv;
        }
    }
}

// ---------------- MFMA flash attention v4: split-K for qt>=16 (verified R6) ----------------
__global__ __launch_bounds__(256) void attn_mfma4(const unsigned short* __restrict__ Qh,
                                                  const unsigned short* __restrict__ Kf,
                                                  const unsigned short* __restrict__ Vf,
                                                  float* __restrict__ ao,
                                                  float* __restrict__ Po,
                                                  float* __restrict__ Pm,
                                                  float* __restrict__ Pl){
    __shared__ s16x8 Kbuf[2][512];
    __shared__ s16x8 Vbuf[2][512];
    int blk = blockIdx.x;
    int bh = blk & 31;
    int s_ = blk >> 5;
    int part = (s_ >= 32);
    int qt = part ? (63 - s_) : (31 - s_);
    int h1 = (qt < 16) ? (qt + 1) : ((qt + 1) >> 1);
    int k0 = part ? h1 : 0;
    int k1 = part ? (qt + 1) : h1;
    int n = k1 - k0;
    int b  = bh >> 4;
    int tid = threadIdx.x;
    int w = tid >> 6, lane = tid & 63;
    int m = lane & 15, g = lane >> 4;
    int q = qt*64 + w*16 + m;

    const unsigned short* Qhead = Qh + (size_t)bh*TT*HD;
    const s16x8* Kbase = (const s16x8*)(Kf + (size_t)bh*32*4096);
    const s16x8* Vbase = (const s16x8*)(Vf + (size_t)bh*32*4096);

    s16x8 Qf0 = *(const s16x8*)(Qhead + (size_t)q*HD + g*8);
    s16x8 Qf1 = *(const s16x8*)(Qhead + (size_t)q*HD + g*8 + 32);

    f32x4 Of[4] = {f32x4{0,0,0,0}, f32x4{0,0,0,0}, f32x4{0,0,0,0}, f32x4{0,0,0,0}};
    float mrow = -1e30f, lrow = 0.f;

    #pragma unroll
    for(int r=0;r<2;r++){
        gload16((const char*)(Kbase + (size_t)k0*512) + ((r*4 + w)*64 + lane)*16, (char*)Kbuf[0] + (r*4 + w)*1024);
        gload16((const char*)(Vbase + (size_t)k0*512) + ((r*4 + w)*64 + lane)*16, (char*)Vbuf[0] + (r*4 + w)*1024);
    }

    for(int i=0; i<n; i++){
        int kt = k0 + i;
        __syncthreads();
        if (i+1 < n){
            int nb = (i+1)&1;
            const char* kg = (const char*)(Kbase + (size_t)(kt+1)*512);
            const char* vg = (const char*)(Vbase + (size_t)(kt+1)*512);
            #pragma unroll
            for(int r=0;r<2;r++){
                gload16(kg + ((r*4 + w)*64 + lane)*16, (char*)Kbuf[nb] + (r*4 + w)*1024);
                gload16(vg + ((r*4 + w)*64 + lane)*16, (char*)Vbuf[nb] + (r*4 + w)*1024);
            }
        }
        const s16x8* Kc = Kbuf[i&1];
        const s16x8* Vc = Vbuf[i&1];

        f32x4 S[4];
        #pragma unroll
        for(int f=0; f<4; f++){
            s16x8 kk0 = Kc[(f*2+0)*64 + lane];
            s16x8 kk1 = Kc[(f*2+1)*64 + lane];
            f32x4 acc = {0,0,0,0};
            acc = __builtin_amdgcn_mfma_f32_16x16x32_bf16(kk0, Qf0, acc, 0, 0, 0);
            acc = __builtin_amdgcn_mfma_f32_16x16x32_bf16(kk1, Qf1, acc, 0, 0, 0);
            S[f] = acc;
        }

        float p[4][4];
        float mloc = -1e30f;
        if (kt == qt){
            #pragma unroll
            for(int f=0; f<4; f++)
                #pragma unroll
                for(int r=0; r<4; r++){
                    int key = 16*f + 4*g + r;
                    float sv = (qt*64 + key > q) ? -1e30f : S[f][r];
                    p[f][r] = sv;
                    mloc = fmaxf(mloc, sv);
                }
        } else {
            #pragma unroll
            for(int f=0; f<4; f++)
                #pragma unroll
                for(int r=0; r<4; r++){
                    p[f][r] = S[f][r];
                    mloc = fmaxf(mloc, S[f][r]);
                }
        }
        mloc = fmaxf(mloc, __shfl_xor(mloc, 16));
        mloc = fmaxf(mloc, __shfl_xor(mloc, 32));
        float mn = fmaxf(mrow, mloc);
        float alpha = fexp2(mrow - mn);
        float ps = 0.f;
        #pragma unroll
        for(int f=0; f<4; f++)
            #pragma unroll
            for(int r=0; r<4; r++){
                float e = fexp2(p[f][r] - mn);
                p[f][r] = e;
                ps += e;
            }
        ps += __shfl_xor(ps, 16);
        ps += __shfl_xor(ps, 32);
        lrow = lrow*alpha + ps;
        mrow = mn;

        #pragma unroll
        for(int f2=0; f2<4; f2++)
            #pragma unroll
            for(int r=0; r<4; r++) Of[f2][r] *= alpha;

        unsigned pp0[4], pp1[4];
        #pragma unroll
        for(int f=0; f<4; f++){
            pp0[f] = pk2(p[f][0], p[f][1]);
            pp1[f] = pk2(p[f][2], p[f][3]);
        }

        int src0 = m + 16*(2*(g&1));
        int src1 = src0 + 16;
        bool hi = (g >= 2);
        #pragma unroll
        for(int c=0; c<2; c++){
            unsigned a0 = (unsigned)__shfl((int)pp0[2*c],   src0);
            unsigned a1 = (unsigned)__shfl((int)pp0[2*c+1], src0);
            unsigned b0 = hi ? a1 : a0;
            unsigned a2 = (unsigned)__shfl((int)pp1[2*c],   src0);
            unsigned a3 = (unsigned)__shfl((int)pp1[2*c+1], src0);
            unsigned b1 = hi ? a3 : a2;
            unsigned a4 = (unsigned)__shfl((int)pp0[2*c],   src1);
            unsigned a5 = (unsigned)__shfl((int)pp0[2*c+1], src1);
            unsigned b2 = hi ? a5 : a4;
            unsigned a6 = (unsigned)__shfl((int)pp1[2*c],   src1);
            unsigned a7 = (unsigned)__shfl((int)pp1[2*c+1], src1);
            unsigned b3 = hi ? a7 : a6;
            union { unsigned u[4]; s16x8 v; } Bf;
            Bf.u[0]=b0; Bf.u[1]=b1; Bf.u[2]=b2; Bf.u[3]=b3;
            #pragma unroll
            for(int f2=0; f2<4; f2++){
                s16x8 vf = Vc[(f2*2+c)*64 + lane];
                Of[f2] = __builtin_amdgcn_mfma_f32_16x16x32_bf16(vf, Bf.v, Of[f2], 0, 0, 0);
            }
        }
    }

    if (qt < 16){
        float invl = 1.0f / lrow;
        size_t obase = (size_t)(b*TT + q)*DIM + (bh & 15)*HD;
        #pragma unroll
        for(int f2=0; f2<4; f2++)
            #pragma unroll
            for(int r=0; r<4; r++)
                ao[obase + 16*f2 + 4*g + r] = Of[f2][r]*invl;
    } else {
        int si = (bh*16 + (qt-16))*2 + part;
        float* Ob = Po + (size_t)si*4096 + (w*16 + m)*64;
        #pragma unroll
        for(int f2=0; f2<4; f2++)
            #pragma unroll
            for(int r=0; r<4; r++)
                Ob[16*f2 + 4*g + r] = Of[f2][r];
        if (g == 0){
            Pm[si*64 + w*16 + m] = mrow;
            Pl[si*64 + w*16 + m] = lrow;
        }
    }
}

// ---------------- merge split-K partials (verified R6) ----------------
__global__ __launch_bounds__(256) void attn_merge(const float* __restrict__ Po,
                                                  const float* __restrict__ Pm,
                                                  const float* __restrict__ Pl,
                                                  float* __restrict__ ao){
    int blk = blockIdx.x;
    int bh = blk >> 4;
    int qti = blk & 15;
    int qt = 16 + qti;
    int b = bh >> 4, h = bh & 15;
    int tid = threadIdx.x;
    int row = tid >> 2;
    int d0 = (tid & 3)*16;
    int si = (bh*16 + qti)*2;
    float m1 = Pm[si*64 + row],     l1 = Pl[si*64 + row];
    float m2 = Pm[(si+1)*64 + row], l2 = Pl[(si+1)*64 + row];
    float mm = fmaxf(m1, m2);
    float w1 = fexp2(m1 - mm), w2 = fexp2(m2 - mm);
    float inv = 1.0f / (w1*l1 + w2*l2);
    const float* O1 = Po + (size_t)si*4096 + row*64 + d0;
    const float* O2 = Po + (size_t)(si+1)*4096 + row*64 + d0;
    int q = qt*64 + row;
    float* outp = ao + (size_t)(b*TT + q)*DIM + h*HD + d0;
    #pragma unroll
    for(int c=0; c<4; c++){
        float4 v1 = *(const float4*)(O1 + c*4);
        float4 v2 = *(const float4*)(O2 + c*4);
        float4 o;
        o.x = (v1.x*w1 + v2.x*w2)*inv;
        o.y = (v1.y*w1 + v2.y*w2)*inv;
        o.z = (v1.z*w1 + v2.z*w2)*inv;
        o.w = (v1.w*w1 + v2.w*w2)*inv;
        *(float4*)(outp + c*4) = o;
    }
}

// ---------------- launch ----------------
extern "C" void kernel_launch(void* const* d_in, const int* in_sizes, int n_in,
                              void* d_out, int out_size, void* d_ws, size_t ws_size,
                              hipStream_t stream){
    const float* x    = (const float*)d_in[0];
    const float* cosb = (const float*)d_in[1];
    const float* sinb = (const float*)d_in[2];
    const float* wq_w = (const float*)d_in[3];
    const float* wk_w = (const float*)d_in[4];
    const float* wv_w = (const float*)d_in[5];
    const float* wo_w = (const float*)d_in[6];
    float* out = (float*)d_out;

    char* cw = (char*)d_ws;
    const size_t MB = 1048576;
    char*  w8all = cw;                             // [0,4MB)
    float* wsall = (float*)(cw + 4*MB);            // 128 KB
    float* srow1 = (float*)(cw + 4*MB + 131072);   // 16 KB
    float* srow2 = (float*)(cw + 4*MB + 147456);   // 16 KB
    char*  xq8   = cw + 5*MB;                      // [5,9MB)
    char*  xq8_2 = cw + 9*MB;                      // [9,13MB)
    unsigned short* Qh = (unsigned short*)(cw + 13*MB);  // [13,21MB)
    unsigned short* Kf = (unsigned short*)(cw + 21*MB);  // [21,29MB)
    unsigned short* Vf = (unsigned short*)(cw + 29*MB);  // [29,37MB)
    float* ao    = (float*)(cw + 37*MB);           // [37,53MB)
    float* Po    = (float*)(cw + 53*MB);           // [53,70MB)
    float* Pm    = (float*)(cw + 70*MB);           // 256 KB
    float* Pl    = (float*)(cw + 70*MB + 262144);  // 256 KB

    quant_all<<<1024 + MROWS, 256, 0, stream>>>(x, wq_w, wk_w, wv_w, wo_w,
                                                w8all, wsall, xq8, srow1);

    gemm_qkv<<<dim3(24, MROWS/64), 256, 0, stream>>>(xq8, w8all, wsall, srow1,
                                                     cosb, sinb, Qh, Kf, Vf);

    attn_mfma4<<<1536, 256, 0, stream>>>(Qh, Kf, Vf, ao, Po, Pm, Pl);
    attn_merge<<<512, 256, 0, stream>>>(Po, Pm, Pl, ao);

    quant_x_i8<<<MROWS, 256, 0, stream>>>(ao, xq8_2, srow2);
    gemm_i8<<<dim3(DIM/128, MROWS/64), 256, 0, stream>>>(xq8_2, w8all + 3*MB,
                                                         wsall + 3*8192, srow2, out);
}